// Round 7
// baseline (1371.372 us; speedup 1.0000x reference)
//
#include <hip/hip_runtime.h>
#include <math.h>

// Problem constants
#define B_ 256
#define T_ 2000
#define I_ 80
#define H_ 20
#define G_ 80      // 4*H
#define M_ 512000  // B*T

#define LOG2E 1.442695041f

typedef __attribute__((ext_vector_type(2))) float f32x2;
typedef __attribute__((ext_vector_type(2))) unsigned u32x2;

__device__ __forceinline__ f32x2 mk2(float a, float b) { f32x2 r; r.x = a; r.y = b; return r; }

// Cross-half value swap: returns, in lanes 0-31, the value held by lane+32.
__device__ __forceinline__ float swap_half(float x, int swapidx) {
#if __has_builtin(__builtin_amdgcn_permlane32_swap)
    u32x2 r = __builtin_amdgcn_permlane32_swap(__float_as_uint(x), __float_as_uint(x), false, false);
    return __uint_as_float(r.y);   // lanes<32: other half's value
#else
    return __uint_as_float((unsigned)__builtin_amdgcn_ds_bpermute(swapidx, (int)__float_as_uint(x)));
#endif
}

// B-fragment LDS layout: chunk-major, stride 332 floats (3-way max conflict).
#define WS2_STRIDE 332
#define WS2_SIZE   6640

// ---------------------------------------------------------------------------
// GEMM (layer 0, row-major A) — unchanged from round 6.
// ---------------------------------------------------------------------------
template<int K>
__global__ __launch_bounds__(256) void gemm_xg(
    const float* __restrict__ X,     // (M, K) row-major
    const float* __restrict__ Wih,   // (2, K, 80)
    const float* __restrict__ Bias,  // (2, 80)
    float* __restrict__ XG,          // (M, 160) permuted+scaled cols
    int M)
{
    constexpr int KC = 40;
    __shared__ float ws2[WS2_SIZE];
    __shared__ float xs[KC][100];
    __shared__ float bs[160];

    const int tid  = threadIdx.x;
    const int row0 = blockIdx.x * 96;
    const int tx = tid % 20;
    const int ty = tid / 20;
    const bool run = (ty < 12);

    if (tid < 160) {
        int dd = (tid >= 80);
        int r = tid - 80 * dd;
        int j = r >> 2, g = r & 3;
        float sc = (g == 2) ? 2.0f * LOG2E : -LOG2E;
        bs[tid] = sc * Bias[dd * 80 + g * 20 + j];
    }

    int nrows = M - row0; if (nrows > 96) nrows = 96;

    f32x2 acc[8][4];
    bool first = true;
    const float* wsp = &ws2[tx * WS2_STRIDE];

    for (int kc = 0; kc < K; kc += KC) {
        for (int idx = tid; idx < KC * 160; idx += 256) {
            int i = idx / 160, cc = idx - 160 * i;
            int dd = (cc >= 80), r = cc - 80 * dd;
            int j = r >> 2, g = r & 3;
            float sc = (g == 2) ? 2.0f * LOG2E : -LOG2E;
            ws2[(cc >> 3) * WS2_STRIDE + i * 8 + (cc & 7)] =
                sc * Wih[(dd * K + kc + i) * 80 + g * 20 + j];
        }
        for (int i4 = tid; i4 < (96 * KC) / 4; i4 += 256) {
            int r = i4 / 10;
            int kk = (i4 - 10 * r) * 4;
            float4 v = make_float4(0.f, 0.f, 0.f, 0.f);
            if (r < nrows)
                v = *(const float4*)(X + (long long)(row0 + r) * K + kc + kk);
            xs[kk][r] = v.x; xs[kk + 1][r] = v.y; xs[kk + 2][r] = v.z; xs[kk + 3][r] = v.w;
        }
        __syncthreads();

        if (first) {
            first = false;
            #pragma unroll
            for (int p = 0; p < 4; ++p) {
                const f32x2 bv = mk2(bs[tx * 8 + 2 * p], bs[tx * 8 + 2 * p + 1]);
                #pragma unroll
                for (int r = 0; r < 8; ++r) acc[r][p] = bv;
            }
        }

        if (run) {
            #pragma unroll 4
            for (int k = 0; k < KC; ++k) {
                float a[8];
                f32x2 b2[4];
                *(float4*)&a[0]  = *(const float4*)&xs[k][ty * 8];
                *(float4*)&a[4]  = *(const float4*)&xs[k][ty * 8 + 4];
                *(float4*)&b2[0] = *(const float4*)&wsp[k * 8];
                *(float4*)&b2[2] = *(const float4*)&wsp[k * 8 + 4];
                #pragma unroll
                for (int r = 0; r < 8; ++r) {
                    const f32x2 av = mk2(a[r], a[r]);
                    #pragma unroll
                    for (int p = 0; p < 4; ++p)
                        acc[r][p] = __builtin_elementwise_fma(av, b2[p], acc[r][p]);
                }
            }
        }
        __syncthreads();
    }

    if (run) {
        #pragma unroll
        for (int r = 0; r < 8; ++r) {
            int row = row0 + ty * 8 + r;
            if (row < M) {
                float* dst = XG + (long long)row * 160 + tx * 8;
                *(float4*)(dst)     = *(float4*)&acc[r][0];
                *(float4*)(dst + 4) = *(float4*)&acc[r][2];
            }
        }
    }
}

// ---------------------------------------------------------------------------
// LSTM scan v10 body as a device function (one direction, gate-split halves).
// Instruction stream and accumulation order EXACTLY as the measured-406us v10.
// ---------------------------------------------------------------------------
__device__ __forceinline__ void scan_dir(
    const float* __restrict__ xg,    // (B,T,2,20,4) scaled, unit-major
    const float* __restrict__ w_hh,  // (2, 20, 80) natural (k, g*20+j)
    float* __restrict__ h_out,       // (B, 40, T)
    int T, int b, int d, int lane)
{
    const int half = lane >> 5;           // 0: gates i,f   1: gates g,o
    const int j    = lane & 31;
    const bool act_lane = (lane < H_);    // lanes 0..19 hold h / store
    const int jj   = (j < H_) ? j : 0;
    const bool isB = (d == 1);

    const int swapidx = ((lane + 32) & 63) << 2;   // bpermute fallback index

    const int gA = half ? 2 : 0;
    const int gB = gA + 1;
    const float scA = half ? (2.0f * LOG2E) : (-LOG2E);
    const float scB = -LOG2E;

    f32x2 wA[10], wB[10];
    const float* wb = w_hh + d * (H_ * G_);
    #pragma unroll
    for (int i = 0; i < 10; ++i) {
        wA[i] = mk2(scA * wb[(2 * i) * G_ + gA * 20 + jj],
                    scA * wb[(2 * i + 1) * G_ + gA * 20 + jj]);
        wB[i] = mk2(scB * wb[(2 * i) * G_ + gB * 20 + jj],
                    scB * wb[(2 * i + 1) * G_ + gB * 20 + jj]);
    }

    float sh[20];
    #pragma unroll
    for (int k = 0; k < 20; ++k) sh[k] = 0.f;
    float c = 0.f;

    const int t0    = isB ? (T - 1) : 0;
    const int rstep = isB ? -160 : 160;
    const float* pf = xg + ((long long)(b * T + t0) * 2 + d) * 80 + 4 * jj + 2 * half;

    float* hp = h_out + ((long long)b * 40 + d * 20 + jj) * T + (isB ? T - 4 : 0);
    const int hgstep = isB ? -4 : 4;

    constexpr int PF = 8;
    f32x2 px[PF];
    #pragma unroll
    for (int s = 0; s < PF; ++s) { px[s] = *(const f32x2*)pf; pf += rstep; }

    float hq0 = 0.f, hq1 = 0.f, hq2 = 0.f, hq3 = 0.f;

    for (int tb = 0; tb < T; tb += PF) {
        #pragma unroll
        for (int s = 0; s < PF; ++s) {
            const f32x2 v = px[s];
            px[s] = *(const f32x2*)pf; pf += rstep;   // prefetch t+PF

            f32x2 aA1 = mk2(v.x, 0.f);
            f32x2 aA2 = mk2(0.f, 0.f);
            f32x2 aB1 = mk2(v.y, 0.f);
            f32x2 aB2 = mk2(0.f, 0.f);
            #pragma unroll
            for (int i = 0; i < 5; ++i) {
                const f32x2 hlo = mk2(sh[2 * i],      sh[2 * i + 1]);
                const f32x2 hhi = mk2(sh[10 + 2 * i], sh[11 + 2 * i]);
                aA1 = __builtin_elementwise_fma(wA[i],     hlo, aA1);
                aA2 = __builtin_elementwise_fma(wA[i + 5], hhi, aA2);
                aB1 = __builtin_elementwise_fma(wB[i],     hlo, aB1);
                aB2 = __builtin_elementwise_fma(wB[i + 5], hhi, aB2);
            }
            const f32x2 tA = aA1 + aA2;
            const f32x2 tB = aB1 + aB2;
            const float mA = tA.x + tA.y;
            const float mB = tB.x + tB.y;

            const float sA = __builtin_amdgcn_rcpf(1.0f + __builtin_amdgcn_exp2f(mA));
            const float sB = __builtin_amdgcn_rcpf(1.0f + __builtin_amdgcn_exp2f(mB));

            const float sAx = swap_half(sA, swapidx);  // low: sig(m_g)
            const float gox = swap_half(sB, swapidx);  // low: go

            const float gg = fmaf(-2.0f, sAx, 1.0f);
            c = fmaf(sB, c, sA * gg);
            const float th = fmaf(-2.0f,
                __builtin_amdgcn_rcpf(1.0f + __builtin_amdgcn_exp2f(2.0f * LOG2E * c)), 1.0f);
            const float hj = gox * th;                 // valid in lanes 0..19

            {
                const int p = s & 3;
                if (p == 0) hq0 = hj;
                else if (p == 1) hq1 = hj;
                else if (p == 2) hq2 = hj;
                else {
                    hq3 = hj;
                    float4 sv;
                    sv.x = isB ? hq3 : hq0;
                    sv.y = isB ? hq2 : hq1;
                    sv.z = isB ? hq1 : hq2;
                    sv.w = isB ? hq0 : hq3;
                    if (act_lane) *(float4*)hp = sv;
                    hp += hgstep;
                }
            }

            #pragma unroll
            for (int k = 0; k < 20; ++k)
                sh[k] = __uint_as_float(__builtin_amdgcn_readlane(__float_as_uint(hj), k));
        }
    }
}

// ---------------------------------------------------------------------------
// Kernel A: scan layer-0 (waves 0-1) + fused gemm1 tail (all 8 waves).
// Waves 2-7 stage W1/bias into LDS during the scan, then the whole block
// computes xg1[b] = h0t[b]^T @ W1 + bias, overwriting xg[b] in place.
// Per-batch independent: no cross-block hazards (prefetch overruns read
// garbage that is never consumed).
// ---------------------------------------------------------------------------
__global__ __launch_bounds__(512) void scan0_gemm1(
    float* __restrict__ xg,          // in: layer0 gates; out: layer1 gates
    const float* __restrict__ whh0,  // (2,20,80)
    const float* __restrict__ wih1,  // (2,40,80)
    const float* __restrict__ b1,    // (2,80)
    float* __restrict__ h0t,         // (B,40,T)
    int T)
{
    __shared__ float ws2s[WS2_SIZE];
    __shared__ float xs[40][100];
    __shared__ float bs[160];

    const int b   = blockIdx.x;
    const int tid = threadIdx.x;

    if (tid >= 128) {
        // stage W1 (scaled, swizzled) + bias while waves 0-1 scan
        for (int idx = tid - 128; idx < 40 * 160; idx += 384) {
            int i = idx / 160, cc = idx - 160 * i;
            int dd = (cc >= 80), r = cc - 80 * dd;
            int jc = r >> 2, g = r & 3;
            float sc = (g == 2) ? 2.0f * LOG2E : -LOG2E;
            ws2s[(cc >> 3) * WS2_STRIDE + i * 8 + (cc & 7)] =
                sc * wih1[(dd * 40 + i) * 80 + g * 20 + jc];
        }
        if (tid - 128 < 160) {
            int cidx = tid - 128;
            int dd = (cidx >= 80);
            int r = cidx - 80 * dd;
            int jc = r >> 2, g = r & 3;
            float sc = (g == 2) ? 2.0f * LOG2E : -LOG2E;
            bs[cidx] = sc * b1[dd * 80 + g * 20 + jc];
        }
    } else {
        scan_dir(xg, whh0, h0t, T, b, tid >> 6, tid & 63);
    }
    __syncthreads();

    // ---- gemm1 tail: 21 t-tiles of 96 rows ----
    const int tx  = tid % 20;
    const int tyy = tid / 20;
    const bool run = (tyy < 24);
    const float* wsp = &ws2s[tx * WS2_STRIDE];

    for (int tc = 0; tc < 21; ++tc) {
        const int t0 = tc * 96;
        int nrows = T - t0; if (nrows > 96) nrows = 96;   // 96 or 80

        for (int i4 = tid; i4 < 40 * 24; i4 += 512) {
            int k = i4 / 24;
            int r = (i4 - 24 * k) * 4;
            float4 v = make_float4(0.f, 0.f, 0.f, 0.f);
            if (r < nrows)
                v = *(const float4*)(h0t + ((long long)b * 40 + k) * T + t0 + r);
            *(float4*)&xs[k][r] = v;
        }
        __syncthreads();

        if (run) {
            f32x2 acc[4][4];
            #pragma unroll
            for (int p = 0; p < 4; ++p) {
                const f32x2 bv = mk2(bs[tx * 8 + 2 * p], bs[tx * 8 + 2 * p + 1]);
                #pragma unroll
                for (int r = 0; r < 4; ++r) acc[r][p] = bv;
            }
            #pragma unroll 4
            for (int k = 0; k < 40; ++k) {
                float a[4];
                f32x2 b2[4];
                *(float4*)&a[0]  = *(const float4*)&xs[k][tyy * 4];
                *(float4*)&b2[0] = *(const float4*)&wsp[k * 8];
                *(float4*)&b2[2] = *(const float4*)&wsp[k * 8 + 4];
                #pragma unroll
                for (int r = 0; r < 4; ++r) {
                    const f32x2 av = mk2(a[r], a[r]);
                    #pragma unroll
                    for (int p = 0; p < 4; ++p)
                        acc[r][p] = __builtin_elementwise_fma(av, b2[p], acc[r][p]);
                }
            }
            #pragma unroll
            for (int r = 0; r < 4; ++r) {
                int rr = tyy * 4 + r;
                if (rr < nrows) {
                    long long row = (long long)b * T + t0 + rr;
                    float* dst = xg + row * 160 + tx * 8;
                    *(float4*)(dst)     = *(float4*)&acc[r][0];
                    *(float4*)(dst + 4) = *(float4*)&acc[r][2];
                }
            }
        }
        __syncthreads();
    }
}

// ---------------------------------------------------------------------------
// Kernel B: scan layer-1 (waves 0-1) + fused FC tail (500 threads).
// ---------------------------------------------------------------------------
__global__ __launch_bounds__(512) void scan1_fc(
    const float* __restrict__ xg,    // layer-1 gates
    const float* __restrict__ whh1,  // (2,20,80)
    const float* __restrict__ fcw,   // (40,)
    const float* __restrict__ fcb,   // (1,)
    float* __restrict__ h1t,         // (B,40,T) scratch
    float* __restrict__ out,         // (B,T)
    int T)
{
    const int b   = blockIdx.x;
    const int tid = threadIdx.x;

    if (tid < 128)
        scan_dir(xg, whh1, h1t, T, b, tid >> 6, tid & 63);
    __syncthreads();

    const int t = tid * 4;
    if (t <= T - 4) {
        const float bias = fcb[0];
        float4 acc = make_float4(bias, bias, bias, bias);
        const float* base = h1t + (long long)b * 40 * T + t;
        #pragma unroll 8
        for (int u = 0; u < 40; ++u) {
            const float wv = fcw[u];
            const float4 hv = *(const float4*)(base + (long long)u * T);
            acc.x = fmaf(hv.x, wv, acc.x);
            acc.y = fmaf(hv.y, wv, acc.y);
            acc.z = fmaf(hv.z, wv, acc.z);
            acc.w = fmaf(hv.w, wv, acc.w);
        }
        *(float4*)(out + (long long)b * T + t) = acc;
    }
}

// ---------------------------------------------------------------------------
extern "C" void kernel_launch(void* const* d_in, const int* in_sizes, int n_in,
                              void* d_out, int out_size, void* d_ws, size_t ws_size,
                              hipStream_t stream) {
    const float* x     = (const float*)d_in[0];
    const float* wih0  = (const float*)d_in[1];
    const float* whh0  = (const float*)d_in[2];
    const float* b0    = (const float*)d_in[3];
    const float* wih1  = (const float*)d_in[4];
    const float* whh1  = (const float*)d_in[5];
    const float* b1    = (const float*)d_in[6];
    const float* fcw   = (const float*)d_in[7];
    const float* fcb   = (const float*)d_in[8];
    float* out = (float*)d_out;

    // Workspace (floats): 2048-float pads around xg for the scan's
    // unconditional ±8-step prefetch.
    float* ws  = (float*)d_ws;
    float* xg  = ws + 2048;                  // B*T*2*80 = 81,920,000 floats
    float* h0t = xg + 81920000LL + 2048;     // B*40*T   = 20,480,000 floats
    float* h1t = h0t + 20480000LL;           // B*40*T   = 20,480,000 floats

    const int M = M_;
    const int gemm_grid = (M + 95) / 96;     // 5334

    // Layer 0 GEMM (standalone — pipeline head)
    gemm_xg<80><<<dim3(gemm_grid), dim3(256), 0, stream>>>(x, wih0, b0, xg, M);
    // Layer 0 scan + fused layer-1 GEMM (in-place xg rewrite, per-batch)
    scan0_gemm1<<<dim3(B_), dim3(512), 0, stream>>>(xg, whh0, wih1, b1, h0t, T_);
    // Layer 1 scan + fused FC
    scan1_fc<<<dim3(B_), dim3(512), 0, stream>>>(xg, whh1, fcw, fcb, h1t, out, T_);
}

// Round 8
// 1347.242 us; speedup vs baseline: 1.0179x; 1.0179x over previous
//
#include <hip/hip_runtime.h>
#include <math.h>

// Problem constants
#define B_ 256
#define T_ 2000
#define I_ 80
#define H_ 20
#define G_ 80      // 4*H
#define M_ 512000  // B*T

#define LOG2E 1.442695041f

typedef __attribute__((ext_vector_type(2))) float f32x2;
typedef __attribute__((ext_vector_type(2))) unsigned u32x2;

__device__ __forceinline__ f32x2 mk2(float a, float b) { f32x2 r; r.x = a; r.y = b; return r; }

// Cross-half value swap: returns, in lanes 0-31, the value held by lane+32.
__device__ __forceinline__ float swap_half(float x, int swapidx) {
#if __has_builtin(__builtin_amdgcn_permlane32_swap)
    u32x2 r = __builtin_amdgcn_permlane32_swap(__float_as_uint(x), __float_as_uint(x), false, false);
    return __uint_as_float(r.y);   // lanes<32: other half's value
#else
    return __uint_as_float((unsigned)__builtin_amdgcn_ds_bpermute(swapidx, (int)__float_as_uint(x)));
#endif
}

// B-fragment LDS layouts (chunk-major). Read addr = tx*STRIDE + k*8:
// STRIDE%32 != 0 cycles bank spans -> ~3-way max conflict.
#define WS2_STRIDE 332    // K=40 variant (fused gemm1 tail)
#define WS2_SIZE   6640
#define WSF_STRIDE 644    // K=80 variant (persistent gemm0): 80*8+4
#define WSF_SIZE   12880  // 20*644

// ---------------------------------------------------------------------------
// GEMM layer 0, PERSISTENT-W: each block stages the full scaled/swizzled W
// (K=80, all 160 cols, 51.5KB) ONCE, then grid-strides over 96-row tiles,
// staging only X per tile. Kills the per-block div/mod-heavy W staging that
// dominated the old version (5334 blocks x 2 chunks of it).
// ---------------------------------------------------------------------------
__global__ __launch_bounds__(256) void gemm_xg_p(
    const float* __restrict__ X,     // (M, 80) row-major
    const float* __restrict__ Wih,   // (2, 80, 80)
    const float* __restrict__ Bias,  // (2, 80)
    float* __restrict__ XG,          // (M, 160) permuted+scaled cols
    int M, int ntiles, int nblocks)
{
    constexpr int K = 80;
    __shared__ float wsf[WSF_SIZE];
    __shared__ float xs[40][100];
    __shared__ float bs[160];

    const int tid = threadIdx.x;
    const int tx  = tid % 20;
    const int ty  = tid / 20;
    const bool run = (ty < 12);

    // ---- stage full W (once per block) + bias ----
    for (int idx = tid; idx < K * 160; idx += 256) {
        int i = idx / 160, cc = idx - 160 * i;
        int dd = (cc >= 80), r = cc - 80 * dd;
        int j = r >> 2, g = r & 3;
        float sc = (g == 2) ? 2.0f * LOG2E : -LOG2E;
        wsf[(cc >> 3) * WSF_STRIDE + i * 8 + (cc & 7)] =
            sc * Wih[(dd * K + i) * 80 + g * 20 + j];
    }
    if (tid < 160) {
        int dd = (tid >= 80);
        int r = tid - 80 * dd;
        int j = r >> 2, g = r & 3;
        float sc = (g == 2) ? 2.0f * LOG2E : -LOG2E;
        bs[tid] = sc * Bias[dd * 80 + g * 20 + j];
    }
    __syncthreads();

    const float* wsp = &wsf[tx * WSF_STRIDE];
    const f32x2 bv0 = mk2(bs[tx * 8 + 0], bs[tx * 8 + 1]);
    const f32x2 bv1 = mk2(bs[tx * 8 + 2], bs[tx * 8 + 3]);
    const f32x2 bv2 = mk2(bs[tx * 8 + 4], bs[tx * 8 + 5]);
    const f32x2 bv3 = mk2(bs[tx * 8 + 6], bs[tx * 8 + 7]);

    for (int tile = blockIdx.x; tile < ntiles; tile += nblocks) {
        const int row0 = tile * 96;
        int nrows = M - row0; if (nrows > 96) nrows = 96;

        f32x2 acc[8][4];
        #pragma unroll
        for (int r = 0; r < 8; ++r) {
            acc[r][0] = bv0; acc[r][1] = bv1; acc[r][2] = bv2; acc[r][3] = bv3;
        }

        #pragma unroll
        for (int kc = 0; kc < K; kc += 40) {
            // stage X chunk: xs[k][r] = X[row0+r][kc+k]
            for (int i4 = tid; i4 < (96 * 40) / 4; i4 += 256) {
                int r = i4 / 10;
                int kk = (i4 - 10 * r) * 4;
                float4 v = make_float4(0.f, 0.f, 0.f, 0.f);
                if (r < nrows)
                    v = *(const float4*)(X + (long long)(row0 + r) * K + kc + kk);
                xs[kk][r] = v.x; xs[kk + 1][r] = v.y; xs[kk + 2][r] = v.z; xs[kk + 3][r] = v.w;
            }
            __syncthreads();

            if (run) {
                const float* wck = wsp + kc * 8;
                #pragma unroll 4
                for (int k = 0; k < 40; ++k) {
                    float a[8];
                    f32x2 b2[4];
                    *(float4*)&a[0]  = *(const float4*)&xs[k][ty * 8];
                    *(float4*)&a[4]  = *(const float4*)&xs[k][ty * 8 + 4];
                    *(float4*)&b2[0] = *(const float4*)&wck[k * 8];
                    *(float4*)&b2[2] = *(const float4*)&wck[k * 8 + 4];
                    #pragma unroll
                    for (int r = 0; r < 8; ++r) {
                        const f32x2 av = mk2(a[r], a[r]);
                        #pragma unroll
                        for (int p = 0; p < 4; ++p)
                            acc[r][p] = __builtin_elementwise_fma(av, b2[p], acc[r][p]);
                    }
                }
            }
            __syncthreads();
        }

        if (run) {
            #pragma unroll
            for (int r = 0; r < 8; ++r) {
                int row = row0 + ty * 8 + r;
                if (row < M) {
                    float* dst = XG + (long long)row * 160 + tx * 8;
                    *(float4*)(dst)     = *(float4*)&acc[r][0];
                    *(float4*)(dst + 4) = *(float4*)&acc[r][2];
                }
            }
        }
    }
}

// ---------------------------------------------------------------------------
// LSTM scan v10 body as a device function (one direction, gate-split halves).
// Instruction stream and accumulation order EXACTLY as the measured-406us v10.
// ---------------------------------------------------------------------------
__device__ __forceinline__ void scan_dir(
    const float* __restrict__ xg,    // (B,T,2,20,4) scaled, unit-major
    const float* __restrict__ w_hh,  // (2, 20, 80) natural (k, g*20+j)
    float* __restrict__ h_out,       // (B, 40, T)
    int T, int b, int d, int lane)
{
    const int half = lane >> 5;           // 0: gates i,f   1: gates g,o
    const int j    = lane & 31;
    const bool act_lane = (lane < H_);    // lanes 0..19 hold h / store
    const int jj   = (j < H_) ? j : 0;
    const bool isB = (d == 1);

    const int swapidx = ((lane + 32) & 63) << 2;   // bpermute fallback index

    const int gA = half ? 2 : 0;
    const int gB = gA + 1;
    const float scA = half ? (2.0f * LOG2E) : (-LOG2E);
    const float scB = -LOG2E;

    f32x2 wA[10], wB[10];
    const float* wb = w_hh + d * (H_ * G_);
    #pragma unroll
    for (int i = 0; i < 10; ++i) {
        wA[i] = mk2(scA * wb[(2 * i) * G_ + gA * 20 + jj],
                    scA * wb[(2 * i + 1) * G_ + gA * 20 + jj]);
        wB[i] = mk2(scB * wb[(2 * i) * G_ + gB * 20 + jj],
                    scB * wb[(2 * i + 1) * G_ + gB * 20 + jj]);
    }

    float sh[20];
    #pragma unroll
    for (int k = 0; k < 20; ++k) sh[k] = 0.f;
    float c = 0.f;

    const int t0    = isB ? (T - 1) : 0;
    const int rstep = isB ? -160 : 160;
    const float* pf = xg + ((long long)(b * T + t0) * 2 + d) * 80 + 4 * jj + 2 * half;

    float* hp = h_out + ((long long)b * 40 + d * 20 + jj) * T + (isB ? T - 4 : 0);
    const int hgstep = isB ? -4 : 4;

    constexpr int PF = 8;
    f32x2 px[PF];
    #pragma unroll
    for (int s = 0; s < PF; ++s) { px[s] = *(const f32x2*)pf; pf += rstep; }

    float hq0 = 0.f, hq1 = 0.f, hq2 = 0.f, hq3 = 0.f;

    for (int tb = 0; tb < T; tb += PF) {
        #pragma unroll
        for (int s = 0; s < PF; ++s) {
            const f32x2 v = px[s];
            px[s] = *(const f32x2*)pf; pf += rstep;   // prefetch t+PF

            f32x2 aA1 = mk2(v.x, 0.f);
            f32x2 aA2 = mk2(0.f, 0.f);
            f32x2 aB1 = mk2(v.y, 0.f);
            f32x2 aB2 = mk2(0.f, 0.f);
            #pragma unroll
            for (int i = 0; i < 5; ++i) {
                const f32x2 hlo = mk2(sh[2 * i],      sh[2 * i + 1]);
                const f32x2 hhi = mk2(sh[10 + 2 * i], sh[11 + 2 * i]);
                aA1 = __builtin_elementwise_fma(wA[i],     hlo, aA1);
                aA2 = __builtin_elementwise_fma(wA[i + 5], hhi, aA2);
                aB1 = __builtin_elementwise_fma(wB[i],     hlo, aB1);
                aB2 = __builtin_elementwise_fma(wB[i + 5], hhi, aB2);
            }
            const f32x2 tA = aA1 + aA2;
            const f32x2 tB = aB1 + aB2;
            const float mA = tA.x + tA.y;
            const float mB = tB.x + tB.y;

            const float sA = __builtin_amdgcn_rcpf(1.0f + __builtin_amdgcn_exp2f(mA));
            const float sB = __builtin_amdgcn_rcpf(1.0f + __builtin_amdgcn_exp2f(mB));

            const float sAx = swap_half(sA, swapidx);  // low: sig(m_g)
            const float gox = swap_half(sB, swapidx);  // low: go

            const float gg = fmaf(-2.0f, sAx, 1.0f);
            c = fmaf(sB, c, sA * gg);
            const float th = fmaf(-2.0f,
                __builtin_amdgcn_rcpf(1.0f + __builtin_amdgcn_exp2f(2.0f * LOG2E * c)), 1.0f);
            const float hj = gox * th;                 // valid in lanes 0..19

            {
                const int p = s & 3;
                if (p == 0) hq0 = hj;
                else if (p == 1) hq1 = hj;
                else if (p == 2) hq2 = hj;
                else {
                    hq3 = hj;
                    float4 sv;
                    sv.x = isB ? hq3 : hq0;
                    sv.y = isB ? hq2 : hq1;
                    sv.z = isB ? hq1 : hq2;
                    sv.w = isB ? hq0 : hq3;
                    if (act_lane) *(float4*)hp = sv;
                    hp += hgstep;
                }
            }

            #pragma unroll
            for (int k = 0; k < 20; ++k)
                sh[k] = __uint_as_float(__builtin_amdgcn_readlane(__float_as_uint(hj), k));
        }
    }
}

// ---------------------------------------------------------------------------
// Kernel A: scan layer-0 (waves 0-1) + fused gemm1 tail (all 8 waves).
// amdgpu_waves_per_eu(2,2): 8 waves on 4 EUs = 2/EU -> VGPR budget 256/wave.
// Round-7's default allocation (52 VGPR) spilled the scan's weights/prefetch
// to scratch on the serial recurrence path (565us). This pins the budget.
// ---------------------------------------------------------------------------
__attribute__((amdgpu_waves_per_eu(2, 2)))
__global__ __launch_bounds__(512) void scan0_gemm1(
    float* __restrict__ xg,          // in: layer0 gates; out: layer1 gates
    const float* __restrict__ whh0,  // (2,20,80)
    const float* __restrict__ wih1,  // (2,40,80)
    const float* __restrict__ b1,    // (2,80)
    float* __restrict__ h0t,         // (B,40,T)
    int T)
{
    __shared__ float ws2s[WS2_SIZE];
    __shared__ float xs[40][100];
    __shared__ float bs[160];

    const int b   = blockIdx.x;
    const int tid = threadIdx.x;

    if (tid >= 128) {
        // stage W1 (scaled, swizzled) + bias while waves 0-1 scan
        for (int idx = tid - 128; idx < 40 * 160; idx += 384) {
            int i = idx / 160, cc = idx - 160 * i;
            int dd = (cc >= 80), r = cc - 80 * dd;
            int jc = r >> 2, g = r & 3;
            float sc = (g == 2) ? 2.0f * LOG2E : -LOG2E;
            ws2s[(cc >> 3) * WS2_STRIDE + i * 8 + (cc & 7)] =
                sc * wih1[(dd * 40 + i) * 80 + g * 20 + jc];
        }
        if (tid - 128 < 160) {
            int cidx = tid - 128;
            int dd = (cidx >= 80);
            int r = cidx - 80 * dd;
            int jc = r >> 2, g = r & 3;
            float sc = (g == 2) ? 2.0f * LOG2E : -LOG2E;
            bs[cidx] = sc * b1[dd * 80 + g * 20 + jc];
        }
    } else {
        scan_dir(xg, whh0, h0t, T, b, tid >> 6, tid & 63);
    }
    __syncthreads();

    // ---- gemm1 tail: 21 t-tiles of 96 rows ----
    const int tx  = tid % 20;
    const int tyy = tid / 20;
    const bool run = (tyy < 24);
    const float* wsp = &ws2s[tx * WS2_STRIDE];

    for (int tc = 0; tc < 21; ++tc) {
        const int t0 = tc * 96;
        int nrows = T - t0; if (nrows > 96) nrows = 96;   // 96 or 80

        for (int i4 = tid; i4 < 40 * 24; i4 += 512) {
            int k = i4 / 24;
            int r = (i4 - 24 * k) * 4;
            float4 v = make_float4(0.f, 0.f, 0.f, 0.f);
            if (r < nrows)
                v = *(const float4*)(h0t + ((long long)b * 40 + k) * T + t0 + r);
            *(float4*)&xs[k][r] = v;
        }
        __syncthreads();

        if (run) {
            f32x2 acc[4][4];
            #pragma unroll
            for (int p = 0; p < 4; ++p) {
                const f32x2 bv = mk2(bs[tx * 8 + 2 * p], bs[tx * 8 + 2 * p + 1]);
                #pragma unroll
                for (int r = 0; r < 4; ++r) acc[r][p] = bv;
            }
            #pragma unroll 4
            for (int k = 0; k < 40; ++k) {
                float a[4];
                f32x2 b2[4];
                *(float4*)&a[0]  = *(const float4*)&xs[k][tyy * 4];
                *(float4*)&b2[0] = *(const float4*)&wsp[k * 8];
                *(float4*)&b2[2] = *(const float4*)&wsp[k * 8 + 4];
                #pragma unroll
                for (int r = 0; r < 4; ++r) {
                    const f32x2 av = mk2(a[r], a[r]);
                    #pragma unroll
                    for (int p = 0; p < 4; ++p)
                        acc[r][p] = __builtin_elementwise_fma(av, b2[p], acc[r][p]);
                }
            }
            #pragma unroll
            for (int r = 0; r < 4; ++r) {
                int rr = tyy * 4 + r;
                if (rr < nrows) {
                    long long row = (long long)b * T + t0 + rr;
                    float* dst = xg + row * 160 + tx * 8;
                    *(float4*)(dst)     = *(float4*)&acc[r][0];
                    *(float4*)(dst + 4) = *(float4*)&acc[r][2];
                }
            }
        }
        __syncthreads();
    }
}

// ---------------------------------------------------------------------------
// Kernel B: scan layer-1 (waves 0-1) + fused FC tail (500 threads).
// Same waves_per_eu pin as kernel A.
// ---------------------------------------------------------------------------
__attribute__((amdgpu_waves_per_eu(2, 2)))
__global__ __launch_bounds__(512) void scan1_fc(
    const float* __restrict__ xg,    // layer-1 gates
    const float* __restrict__ whh1,  // (2,20,80)
    const float* __restrict__ fcw,   // (40,)
    const float* __restrict__ fcb,   // (1,)
    float* __restrict__ h1t,         // (B,40,T) scratch
    float* __restrict__ out,         // (B,T)
    int T)
{
    const int b   = blockIdx.x;
    const int tid = threadIdx.x;

    if (tid < 128)
        scan_dir(xg, whh1, h1t, T, b, tid >> 6, tid & 63);
    __syncthreads();

    const int t = tid * 4;
    if (t <= T - 4) {
        const float bias = fcb[0];
        float4 acc = make_float4(bias, bias, bias, bias);
        const float* base = h1t + (long long)b * 40 * T + t;
        #pragma unroll 8
        for (int u = 0; u < 40; ++u) {
            const float wv = fcw[u];
            const float4 hv = *(const float4*)(base + (long long)u * T);
            acc.x = fmaf(hv.x, wv, acc.x);
            acc.y = fmaf(hv.y, wv, acc.y);
            acc.z = fmaf(hv.z, wv, acc.z);
            acc.w = fmaf(hv.w, wv, acc.w);
        }
        *(float4*)(out + (long long)b * T + t) = acc;
    }
}

// ---------------------------------------------------------------------------
extern "C" void kernel_launch(void* const* d_in, const int* in_sizes, int n_in,
                              void* d_out, int out_size, void* d_ws, size_t ws_size,
                              hipStream_t stream) {
    const float* x     = (const float*)d_in[0];
    const float* wih0  = (const float*)d_in[1];
    const float* whh0  = (const float*)d_in[2];
    const float* b0    = (const float*)d_in[3];
    const float* wih1  = (const float*)d_in[4];
    const float* whh1  = (const float*)d_in[5];
    const float* b1    = (const float*)d_in[6];
    const float* fcw   = (const float*)d_in[7];
    const float* fcb   = (const float*)d_in[8];
    float* out = (float*)d_out;

    // Workspace (floats): 2048-float pads around xg for the scan's
    // unconditional ±8-step prefetch.
    float* ws  = (float*)d_ws;
    float* xg  = ws + 2048;                  // B*T*2*80 = 81,920,000 floats
    float* h0t = xg + 81920000LL + 2048;     // B*40*T   = 20,480,000 floats
    float* h1t = h0t + 20480000LL;           // B*40*T   = 20,480,000 floats

    const int M = M_;
    const int ntiles = (M + 95) / 96;        // 5334
    const int nblocks = 2048;

    // Layer 0 GEMM (persistent-W, grid-stride over row tiles)
    gemm_xg_p<<<dim3(nblocks), dim3(256), 0, stream>>>(x, wih0, b0, xg, M, ntiles, nblocks);
    // Layer 0 scan + fused layer-1 GEMM (in-place xg rewrite, per-batch)
    scan0_gemm1<<<dim3(B_), dim3(512), 0, stream>>>(xg, whh0, wih1, b1, h0t, T_);
    // Layer 1 scan + fused FC
    scan1_fc<<<dim3(B_), dim3(512), 0, stream>>>(xg, whh1, fcw, fcb, h1t, out, T_);
}